// Round 2
// baseline (4558.994 us; speedup 1.0000x reference)
//
#include <hip/hip_runtime.h>
#include <math.h>

typedef unsigned short u16;
typedef short short8 __attribute__((ext_vector_type(8)));
typedef float floatx4 __attribute__((ext_vector_type(4)));
typedef u16 u16x4 __attribute__((ext_vector_type(4)));

#define L_ 6
#define D_ 1024
#define DFF_ 4096
#define V_ 32000
#define T_ 1024
#define B_ 2
#define H_ 16
#define M_ (B_*T_)

__device__ __forceinline__ float b2f(u16 v){ union{unsigned u; float f;} x; x.u = ((unsigned)v)<<16; return x.f; }
__device__ __forceinline__ u16 f2bf(float f){ union{float f; unsigned u;} x; x.f=f; unsigned r = x.u + 0x7fffu + ((x.u>>16)&1u); return (u16)(r>>16); }

// ---------------- embedding: x = tok_emb[idx] + pos_emb (all fp32) ----------------
__global__ __launch_bounds__(256) void embed_kernel(const int* __restrict__ idx,
    const float* __restrict__ tok, const float* __restrict__ pos, float* __restrict__ x)
{
  int m = blockIdx.x;
  int t = m & (T_-1);
  int id = idx[m];
  int d = threadIdx.x*4;
  floatx4 tv = *(const floatx4*)(tok + (size_t)id*D_ + d);
  floatx4 pv = *(const floatx4*)(pos + (size_t)t*D_ + d);
  floatx4 r = tv + pv;
  *(floatx4*)(x + (size_t)m*D_ + d) = r;
}

// ---------------- layernorm: fp32 in, bf16 out ----------------
__global__ __launch_bounds__(256) void ln_kernel(const float* __restrict__ x,
    const float* __restrict__ w, const float* __restrict__ b, u16* __restrict__ out)
{
  int row = blockIdx.x, tid = threadIdx.x;
  const float* xr = x + (size_t)row*D_;
  floatx4 v = *(const floatx4*)(xr + tid*4);
  float s  = v[0]+v[1]+v[2]+v[3];
  float sq = v[0]*v[0]+v[1]*v[1]+v[2]*v[2]+v[3]*v[3];
  #pragma unroll
  for (int m=32;m>0;m>>=1){ s += __shfl_xor(s,m); sq += __shfl_xor(sq,m); }
  __shared__ float red[8];
  if ((tid&63)==0){ red[tid>>6]=s; red[4+(tid>>6)]=sq; }
  __syncthreads();
  float st  = red[0]+red[1]+red[2]+red[3];
  float sqt = red[4]+red[5]+red[6]+red[7];
  float mu = st*(1.0f/D_);
  float rs = rsqrtf(sqt*(1.0f/D_) - mu*mu + 1e-5f);
  floatx4 wv = *(const floatx4*)(w + tid*4);
  floatx4 bv = *(const floatx4*)(b + tid*4);
  u16x4 o;
  #pragma unroll
  for(int j=0;j<4;j++) o[j] = f2bf((v[j]-mu)*rs*wv[j] + bv[j]);
  *(u16x4*)(out + (size_t)row*D_ + tid*4) = o;
}

// ---------------- bf16 MFMA GEMM: C[M,N] = A[M,K] @ W[N,K]^T ----------------
// A: bf16 (internal activations). Bw: fp32 weights, converted to bf16 on stage.
// mode 1: store fp32   mode 2: gelu -> bf16   mode 3: fp32 C += acc
#define BM 128
#define BN 128
#define BK 32
#define LDP 40  // padded LDS row stride (shorts): 2-way conflicts max (free)

__global__ __launch_bounds__(256) void gemm_bf16(const u16* __restrict__ A,
    const float* __restrict__ Bw, void* __restrict__ Cp,
    int M, int N, int K, int mode)
{
  __shared__ __align__(16) u16 As[BM*LDP];
  __shared__ __align__(16) u16 Bs[BN*LDP];
  int tid = threadIdx.x;
  int n0 = blockIdx.x*BN, m0 = blockIdx.y*BM;
  int w = tid>>6, lane = tid&63, quad = lane>>4, r16 = lane&15;
  int wm = (w>>1)*64, wn = (w&1)*64;
  floatx4 acc[4][4];
  #pragma unroll
  for(int i=0;i<4;i++)
    #pragma unroll
    for(int j=0;j<4;j++) acc[i][j] = (floatx4)0.0f;

  for (int k0=0; k0<K; k0+=BK){
    __syncthreads();
    #pragma unroll
    for (int i=0;i<2;i++){
      int f = i*256 + tid;           // 512 chunks of 8 bf16 per tile
      int r = f>>2, c = (f&3)*8;
      *(short8*)(As + r*LDP + c) = *(const short8*)(A + (size_t)(m0+r)*K + k0 + c);
      const float* bp = Bw + (size_t)(n0+r)*K + k0 + c;
      floatx4 b0 = *(const floatx4*)(bp);
      floatx4 b1 = *(const floatx4*)(bp+4);
      short8 bs;
      #pragma unroll
      for (int j=0;j<4;j++){ bs[j] = (short)f2bf(b0[j]); bs[4+j] = (short)f2bf(b1[j]); }
      *(short8*)(Bs + r*LDP + c) = bs;
    }
    __syncthreads();
    short8 af[4], bfr[4];
    #pragma unroll
    for (int i=0;i<4;i++){
      af[i]  = *(const short8*)(As + (wm + i*16 + r16)*LDP + quad*8);
      bfr[i] = *(const short8*)(Bs + (wn + i*16 + r16)*LDP + quad*8);
    }
    #pragma unroll
    for (int mi=0;mi<4;mi++)
      #pragma unroll
      for (int ni=0;ni<4;ni++)
        acc[mi][ni] = __builtin_amdgcn_mfma_f32_16x16x32_bf16(af[mi], bfr[ni], acc[mi][ni], 0,0,0);
  }

  #pragma unroll
  for (int mi=0;mi<4;mi++){
    #pragma unroll
    for (int ni=0;ni<4;ni++){
      #pragma unroll
      for (int r=0;r<4;r++){
        int m = m0 + wm + mi*16 + quad*4 + r;   // C/D: row = quad*4+reg
        int n = n0 + wn + ni*16 + r16;          //      col = lane&15
        float v = acc[mi][ni][r];
        size_t off = (size_t)m*N + n;
        if (mode==1)      ((float*)Cp)[off] = v;
        else if (mode==2) ((u16*)Cp)[off]   = f2bf(0.5f*v*(1.0f + erff(v*0.70710678118654752f)));
        else              ((float*)Cp)[off] += v;
      }
    }
  }
}

// ---------------- causal attention, online softmax, wave-per-qrow ----------------
// qkv fp32 [M, 3D] layout [q|k|v][h][hd]; out bf16 [M, D]
__global__ __launch_bounds__(256) void attn_kernel(const float* __restrict__ qkv,
    u16* __restrict__ out)
{
  __shared__ float Ks[64*65];
  __shared__ float Vs[64*65];
  __shared__ float qsh[4][64];
  __shared__ float ps[4][64];
  int bh = blockIdx.x, b = bh>>4, h = bh&15;
  int w = threadIdx.x>>6, lane = threadIdx.x&63;
  int q = blockIdx.y*4 + w;
  qsh[w][lane] = qkv[((size_t)(b*T_) + q)*3072 + h*64 + lane];
  float o = 0.f, m_run = -INFINITY, l_run = 0.f;
  int nkb = ((blockIdx.y*4+3)>>6) + 1;
  for (int kb=0; kb<nkb; kb++){
    __syncthreads();   // prev tile fully consumed (and qsh visible on kb=0)
    #pragma unroll
    for (int i=0;i<4;i++){
      int f = i*256 + threadIdx.x;     // 1024 float4 chunks per tile
      int r = f>>4, c = (f&15)*4;
      const float* src = qkv + ((size_t)(b*T_) + kb*64 + r)*3072 + h*64 + c;
      floatx4 kv = *(const floatx4*)(src + D_);
      floatx4 vv = *(const floatx4*)(src + 2*D_);
      int base = r*65 + c;
      #pragma unroll
      for (int j=0;j<4;j++){ Ks[base+j]=kv[j]; Vs[base+j]=vv[j]; }
    }
    __syncthreads();
    int kg = kb*64 + lane;
    float s = 0.f;
    #pragma unroll
    for (int d=0; d<64; d++) s += qsh[w][d]*Ks[lane*65+d];
    s *= 0.125f;
    if (kg > q) s = -INFINITY;
    float mt = s;
    #pragma unroll
    for (int msk=32;msk>0;msk>>=1) mt = fmaxf(mt, __shfl_xor(mt,msk));
    float nm = fmaxf(m_run, mt);
    float alpha = (m_run==-INFINITY) ? 0.f : expf(m_run-nm);
    float p = expf(s-nm);
    float psum = p;
    #pragma unroll
    for (int msk=32;msk>0;msk>>=1) psum += __shfl_xor(psum,msk);
    l_run = l_run*alpha + psum;
    o *= alpha;
    m_run = nm;                       // FIX: was missing -> softmax state never carried
    ps[w][lane] = p;
    __syncthreads();   // ps ordering (uniform across waves)
    #pragma unroll 8
    for (int k=0;k<64;k++) o += ps[w][k]*Vs[k*65+lane];
  }
  out[((size_t)(b*T_)+q)*D_ + h*64 + lane] = f2bf(o/l_run);
}

// ---------------- driver ----------------
extern "C" void kernel_launch(void* const* d_in, const int* in_sizes, int n_in,
                              void* d_out, int out_size, void* d_ws, size_t ws_size,
                              hipStream_t stream)
{
  const int*   idx = (const int*)d_in[0];
  const float* tok = (const float*)d_in[1];
  const float* pos = (const float*)d_in[2];
  const float* ln1w = (const float*)d_in[3];
  const float* ln1b = (const float*)d_in[4];
  const float* qkvw = (const float*)d_in[5];
  const float* outw = (const float*)d_in[6];
  const float* ln2w = (const float*)d_in[7];
  const float* ln2b = (const float*)d_in[8];
  const float* f1w  = (const float*)d_in[9];
  const float* f2w  = (const float*)d_in[10];
  const float* lnfw = (const float*)d_in[11];
  const float* lnfb = (const float*)d_in[12];

  char* ws = (char*)d_ws;
  float* x   = (float*)ws;                      // 8 MB  [2048,1024] fp32 residual stream
  u16*  h    = (u16*) (ws + (size_t)( 8<<20));  // 4 MB  [2048,1024] bf16 LN out
  float* qkv = (float*)(ws + (size_t)(12<<20)); // 24 MB [2048,3072] fp32
  u16*  ao   = (u16*) (ws + (size_t)(36<<20));  // 4 MB  [2048,1024] bf16 attn out
  u16*  ff   = (u16*) (ws + (size_t)(40<<20));  // 16 MB [2048,4096] bf16 gelu out
  if (ws_size < ((size_t)56<<20)) return;

  embed_kernel<<<M_, 256, 0, stream>>>(idx, tok, pos, x);
  for (int l=0; l<L_; l++){
    ln_kernel<<<M_, 256, 0, stream>>>(x, ln1w + l*D_, ln1b + l*D_, h);
    gemm_bf16<<<dim3(3*D_/BN, M_/BM), 256, 0, stream>>>(h, qkvw + (size_t)l*3*D_*D_, qkv, M_, 3*D_, D_, 1);
    attn_kernel<<<dim3(B_*H_, T_/4), 256, 0, stream>>>(qkv, ao);
    gemm_bf16<<<dim3(D_/BN, M_/BM), 256, 0, stream>>>(ao, outw + (size_t)l*D_*D_, x, M_, D_, D_, 3);
    ln_kernel<<<M_, 256, 0, stream>>>(x, ln2w + l*D_, ln2b + l*D_, h);
    gemm_bf16<<<dim3(DFF_/BN, M_/BM), 256, 0, stream>>>(h, f1w + (size_t)l*DFF_*D_, ff, M_, DFF_, D_, 2);
    gemm_bf16<<<dim3(D_/BN, M_/BM), 256, 0, stream>>>(ff, f2w + (size_t)l*D_*DFF_, x, M_, D_, DFF_, 3);
  }
  ln_kernel<<<M_, 256, 0, stream>>>(x, lnfw, lnfb, h);
  gemm_bf16<<<dim3(V_/BN, M_/BM), 256, 0, stream>>>(h, tok, (float*)d_out, M_, V_, D_, 1);
}